// Round 9
// baseline (1036.718 us; speedup 1.0000x reference)
//
#include <hip/hip_runtime.h>
#include <hip/hip_bf16.h>
#include <cstdint>

using bf16 = __hip_bfloat16;
typedef __bf16 bf16x8 __attribute__((ext_vector_type(8)));
typedef float f32x4 __attribute__((ext_vector_type(4)));

constexpr int Hd = 512;
constexpr int Ld = 6;
constexpr int Fd = 2048;
constexpr int Vd = 50304;
constexpr int Vpad = 50432;  // 197*256
constexpr int Md = 4096;     // B*S = 4*1024

// ---------- helpers ----------
__device__ __forceinline__ unsigned short f2b(float x) {
  return __builtin_bit_cast(unsigned short, __float2bfloat16(x));
}

__device__ __forceinline__ float gelu_tanh(float x) {
  const float c = 0.7978845608028654f;  // sqrt(2/pi)
  float x3 = x * x * x;
  return 0.5f * x * (1.0f + tanhf(c * (x + 0.044715f * x3)));
}

__device__ __forceinline__ void load16_lds(const bf16* g, bf16* l) {
  __builtin_amdgcn_global_load_lds(
      (const __attribute__((address_space(1))) void*)g,
      (__attribute__((address_space(3))) void*)l, 16, 0, 0);
}

// ---------- cast fp32 -> bf16 with zero pad tail (for eowB) ----------
__global__ __launch_bounds__(256) void cast8pad(const float* __restrict__ in,
                                                bf16* __restrict__ out, int n8cast,
                                                int n8tot) {
  int i = blockIdx.x * 256 + threadIdx.x;
  if (i >= n8tot) return;
  if (i < n8cast) {
    const float4* p = (const float4*)in;
    float4 a = p[2 * i], b = p[2 * i + 1];
    uint4 o = {(unsigned)f2b(a.x) | ((unsigned)f2b(a.y) << 16),
               (unsigned)f2b(a.z) | ((unsigned)f2b(a.w) << 16),
               (unsigned)f2b(b.x) | ((unsigned)f2b(b.y) << 16),
               (unsigned)f2b(b.z) | ((unsigned)f2b(b.w) << 16)};
    ((uint4*)out)[i] = o;
  } else {
    ((uint4*)out)[i] = uint4{0, 0, 0, 0};
  }
}

// ---------- cast fp32 -> bf16, 8 elems/thread ----------
__global__ __launch_bounds__(256) void cast8(const float* __restrict__ in,
                                             bf16* __restrict__ out, int n8) {
  int i = blockIdx.x * 256 + threadIdx.x;
  if (i >= n8) return;
  const float4* p = (const float4*)in;
  float4 a = p[2 * i], b = p[2 * i + 1];
  uint4 o = {(unsigned)f2b(a.x) | ((unsigned)f2b(a.y) << 16),
             (unsigned)f2b(a.z) | ((unsigned)f2b(a.w) << 16),
             (unsigned)f2b(b.x) | ((unsigned)f2b(b.y) << 16),
             (unsigned)f2b(b.z) | ((unsigned)f2b(b.w) << 16)};
  ((uint4*)out)[i] = o;
}

// ---------- transpose+cast: in (R,C) f32 -> out (C,R) bf16, batched over z ----------
__global__ void transpose_cast(const float* __restrict__ in, bf16* __restrict__ out,
                               int R, int C) {
  __shared__ float tile[32][33];
  int l = blockIdx.z;
  in += (size_t)l * R * C;
  out += (size_t)l * R * C;
  int c0 = blockIdx.x * 32, r0 = blockIdx.y * 32;
#pragma unroll
  for (int i = 0; i < 4; i++) {
    int r = r0 + threadIdx.y + i * 8;
    tile[threadIdx.y + i * 8][threadIdx.x] = in[(size_t)r * C + c0 + threadIdx.x];
  }
  __syncthreads();
#pragma unroll
  for (int i = 0; i < 4; i++) {
    int c = c0 + threadIdx.y + i * 8;
    out[(size_t)c * R + r0 + threadIdx.x] = (bf16)tile[threadIdx.x][threadIdx.y + i * 8];
  }
}

// ---------- embedding gather ----------
__global__ void gather_embed(const int* __restrict__ ids, const float* __restrict__ emb,
                             float* __restrict__ h) {
  int row = blockIdx.x;
  int id = ids[row];
  const float4* src = (const float4*)(emb + (size_t)id * Hd);
  float4* dst = (float4*)(h + (size_t)row * Hd);
  dst[threadIdx.x] = src[threadIdx.x];
}

// ---------- layernorm, one wave per row, with fused split-K reduce ----------
// MODE 0: x = h[row]                         (plain LN)
// MODE 1: x = h + fb[col] + p0 + p1; h = x   (finish gemm2 split-K + residual)
// MODE 2: x = p0 + p1 + fb[col];    h = x    (finish hp split-K, overwrite)
template <int MODE>
__global__ __launch_bounds__(256) void ln_rows(
    const float* __restrict__ h, const float* __restrict__ p0,
    const float* __restrict__ p1, const float* __restrict__ fb,
    const float* __restrict__ w, const float* __restrict__ b,
    float* __restrict__ hout, bf16* __restrict__ y) {
  int row = blockIdx.x * 4 + (threadIdx.x >> 6);
  int lane = threadIdx.x & 63;
  size_t base = (size_t)row * Hd + lane * 8;
  float xv[8];
  if constexpr (MODE == 0) {
    *(float4*)&xv[0] = *(const float4*)(h + base);
    *(float4*)&xv[4] = *(const float4*)(h + base + 4);
  } else {
    float4 q0 = *(const float4*)(p0 + base), q1 = *(const float4*)(p0 + base + 4);
    float4 r0 = *(const float4*)(p1 + base), r1 = *(const float4*)(p1 + base + 4);
    float4 f0 = *(const float4*)(fb + lane * 8), f1 = *(const float4*)(fb + lane * 8 + 4);
    xv[0] = q0.x + r0.x + f0.x; xv[1] = q0.y + r0.y + f0.y;
    xv[2] = q0.z + r0.z + f0.z; xv[3] = q0.w + r0.w + f0.w;
    xv[4] = q1.x + r1.x + f1.x; xv[5] = q1.y + r1.y + f1.y;
    xv[6] = q1.z + r1.z + f1.z; xv[7] = q1.w + r1.w + f1.w;
    if constexpr (MODE == 1) {
      float4 a0 = *(const float4*)(h + base), a1 = *(const float4*)(h + base + 4);
      xv[0] += a0.x; xv[1] += a0.y; xv[2] += a0.z; xv[3] += a0.w;
      xv[4] += a1.x; xv[5] += a1.y; xv[6] += a1.z; xv[7] += a1.w;
    }
    *(float4*)(hout + base) = make_float4(xv[0], xv[1], xv[2], xv[3]);
    *(float4*)(hout + base + 4) = make_float4(xv[4], xv[5], xv[6], xv[7]);
  }
  float s = 0.f;
#pragma unroll
  for (int j = 0; j < 8; j++) s += xv[j];
#pragma unroll
  for (int off = 1; off < 64; off <<= 1) s += __shfl_xor(s, off);
  float mu = s * (1.0f / 512.0f);
  float s2 = 0.f;
#pragma unroll
  for (int j = 0; j < 8; j++) {
    xv[j] -= mu;
    s2 += xv[j] * xv[j];
  }
#pragma unroll
  for (int off = 1; off < 64; off <<= 1) s2 += __shfl_xor(s2, off);
  float scale = rsqrtf(s2 * (1.0f / 512.0f) + 1e-5f);
  float o[8];
#pragma unroll
  for (int j = 0; j < 8; j++) {
    float wj = w[lane * 8 + j], bj = b[lane * 8 + j];
    o[j] = xv[j] * scale * wj + bj;
  }
  uint4 pk = {(unsigned)f2b(o[0]) | ((unsigned)f2b(o[1]) << 16),
              (unsigned)f2b(o[2]) | ((unsigned)f2b(o[3]) << 16),
              (unsigned)f2b(o[4]) | ((unsigned)f2b(o[5]) << 16),
              (unsigned)f2b(o[6]) | ((unsigned)f2b(o[7]) << 16)};
  *(uint4*)(y + base) = pk;
}

// ---------- finish split-K gemm2 of stack1: h += fb + p0 + p1, also emit bf16 ----------
__global__ __launch_bounds__(256) void finish2(
    const float* __restrict__ p0, const float* __restrict__ p1,
    const float* __restrict__ fb, float* __restrict__ h, bf16* __restrict__ hbf) {
  int i = blockIdx.x * 256 + threadIdx.x;  // 8 elems each; grid covers 2M elems
  size_t base = (size_t)i * 8;
  int col = (int)(base & 511);
  float x[8];
#pragma unroll
  for (int j = 0; j < 8; j += 4) {
    float4 a = *(const float4*)(h + base + j);
    float4 q = *(const float4*)(p0 + base + j);
    float4 r = *(const float4*)(p1 + base + j);
    float4 f = *(const float4*)(fb + col + j);
    x[j] = a.x + q.x + r.x + f.x; x[j + 1] = a.y + q.y + r.y + f.y;
    x[j + 2] = a.z + q.z + r.z + f.z; x[j + 3] = a.w + q.w + r.w + f.w;
    *(float4*)(h + base + j) = make_float4(x[j], x[j + 1], x[j + 2], x[j + 3]);
  }
  uint4 pk = {(unsigned)f2b(x[0]) | ((unsigned)f2b(x[1]) << 16),
              (unsigned)f2b(x[2]) | ((unsigned)f2b(x[3]) << 16),
              (unsigned)f2b(x[4]) | ((unsigned)f2b(x[5]) << 16),
              (unsigned)f2b(x[6]) | ((unsigned)f2b(x[7]) << 16)};
  *(uint4*)(hbf + base) = pk;
}

// ============ GEMM kernels: BK=64, conflict-free XOR swizzle ============
// LDS layout per operand tile: rows of 64 bf16 (128B) = 8 chunks of 16B.
// Swizzle (both sides): LDS[row][d] holds global[row][d ^ (row&7)].

// ---------- GEMM 128x64 tile, BK=64, 256 thr, 3-slot counted-vmcnt ----------
// 72 KB LDS -> 2 blocks/CU (8 waves/CU TLP). 4 waves as 2M x 2N (wave 64x32).
// EPI 0: out_bf16 = gelu(acc + bias)
// EPI 4: out_f32[z*M*N + idx] = acc   (split-K partial)
template <int EPI>
__global__ __launch_bounds__(256) void gemm_bt(
    const bf16* __restrict__ A, const bf16* __restrict__ Bt,
    const float* __restrict__ bias, float* __restrict__ outF,
    bf16* __restrict__ outB, int M, int N, int Klen, int lda, int ldb) {
  constexpr int ASZ = 128 * 64;          // 8192 elems
  constexpr int BSZ = 64 * 64;           // 4096 elems
  constexpr int TILE = ASZ + BSZ;        // 24 KB
  __shared__ bf16 lds[3 * TILE];         // 72 KB
  const int tid = threadIdx.x;
  const int wave = tid >> 6;
  const int lane = tid & 63;
  const int wm = (wave >> 1) * 64;
  const int wn = (wave & 1) * 32;

  const int bn = blockIdx.x;
  const int bm = blockIdx.y;
  const int rowA0 = bm * 128;
  const int rowB0 = bn * 64;
  const int k0 = blockIdx.z * Klen;

  const bf16* srcA[4];
#pragma unroll
  for (int r = 0; r < 4; r++) {
    int c = r * 256 + tid;
    int row = c >> 3, d = c & 7;
    int cw = d ^ (row & 7);
    srcA[r] = A + (size_t)(rowA0 + row) * lda + k0 + cw * 8;
  }
  const bf16* srcB[2];
#pragma unroll
  for (int r = 0; r < 2; r++) {
    int c = r * 256 + tid;
    int row = c >> 3, d = c & 7;
    int cw = d ^ (row & 7);
    srcB[r] = Bt + (size_t)(rowB0 + row) * ldb + k0 + cw * 8;
  }

  f32x4 acc[4][2];
#pragma unroll
  for (int i = 0; i < 4; i++)
#pragma unroll
    for (int j = 0; j < 2; j++) acc[i][j] = (f32x4){0.f, 0.f, 0.f, 0.f};

  const int fr = lane & 15;
  const int hi = lane >> 4;
  const int swz = fr & 7;

  auto STAGE = [&](int slot) {
    bf16* dst = lds + slot * TILE;
#pragma unroll
    for (int r = 0; r < 4; r++) {
      load16_lds(srcA[r], dst + (r * 4 + wave) * 512);
      srcA[r] += 64;
    }
#pragma unroll
    for (int r = 0; r < 2; r++) {
      load16_lds(srcB[r], dst + ASZ + (r * 4 + wave) * 512);
      srcB[r] += 64;
    }
  };

  STAGE(0);
  STAGE(1);
  const int nIter = Klen >> 6;
  int cur = 0, stg = 2;
  for (int it = 0; it < nIter; ++it) {
    if (it < nIter - 1)
      asm volatile("s_waitcnt vmcnt(6)" ::: "memory");
    else
      asm volatile("s_waitcnt vmcnt(0)" ::: "memory");
    __builtin_amdgcn_s_barrier();
    __builtin_amdgcn_sched_barrier(0);
    if (it + 2 < nIter) STAGE(stg);
    const bf16* lA = lds + cur * TILE;
    const bf16* lB = lA + ASZ;
#pragma unroll
    for (int ks = 0; ks < 2; ks++) {
      bf16x8 af[4], bfr[2];
#pragma unroll
      for (int f = 0; f < 4; f++) {
        int rowa = wm + f * 16 + fr;
        af[f] = *(const bf16x8*)(lA + rowa * 64 + ((ks * 4 + hi) ^ swz) * 8);
      }
#pragma unroll
      for (int f = 0; f < 2; f++) {
        int rowb = wn + f * 16 + fr;
        bfr[f] = *(const bf16x8*)(lB + rowb * 64 + ((ks * 4 + hi) ^ swz) * 8);
      }
#pragma unroll
      for (int i = 0; i < 4; i++)
#pragma unroll
        for (int j = 0; j < 2; j++)
          acc[i][j] = __builtin_amdgcn_mfma_f32_16x16x32_bf16(af[i], bfr[j], acc[i][j], 0, 0, 0);
    }
    cur = (cur == 2) ? 0 : cur + 1;
    stg = (stg == 2) ? 0 : stg + 1;
  }

  if constexpr (EPI == 4) outF += (size_t)blockIdx.z * M * N;
  const int orow = hi * 4;
  const int ocol = fr;
#pragma unroll
  for (int i = 0; i < 4; i++) {
#pragma unroll
    for (int j = 0; j < 2; j++) {
      int row0 = rowA0 + wm + i * 16 + orow;
      int col = rowB0 + wn + j * 16 + ocol;
#pragma unroll
      for (int q = 0; q < 4; q++) {
        float v = acc[i][j][q];
        size_t idx = (size_t)(row0 + q) * N + col;
        if constexpr (EPI == 0) {
          outB[idx] = (bf16)gelu_tanh(v + bias[col]);
        } else {
          outF[idx] = v;
        }
      }
    }
  }
}

// ---------- GEMM 256x128 tile, BK=64, 512 thr, 3-slot counted-vmcnt (gemm1) ----------
// 8 waves as 4M x 2N. Loads/thread/STAGE: A 4 + B 2 = 6.
template <int EPI>
__global__ __launch_bounds__(512) void gemm_bt256(
    const bf16* __restrict__ A, const bf16* __restrict__ Bt,
    const float* __restrict__ bias, float* __restrict__ outF,
    bf16* __restrict__ outB, int M, int N, int lda, int ldb) {
  constexpr int ASZ = 256 * 64;          // 16384 elems (32 KB)
  constexpr int BSZ = 128 * 64;          // 8192 elems (16 KB)
  constexpr int TILE = ASZ + BSZ;        // 48 KB
  __shared__ bf16 lds[3 * TILE];         // 144 KB
  const int tid = threadIdx.x;
  const int wave = tid >> 6;
  const int lane = tid & 63;
  const int wm = (wave >> 1) * 64;
  const int wn = (wave & 1) * 64;

  const int bn = blockIdx.x;
  const int bm = blockIdx.y;
  const int rowA0 = bm * 256;
  const int rowB0 = bn * 128;

  const bf16* srcA[4];
#pragma unroll
  for (int r = 0; r < 4; r++) {
    int c = r * 512 + tid;
    int row = c >> 3, d = c & 7;
    int cw = d ^ (row & 7);
    srcA[r] = A + (size_t)(rowA0 + row) * lda + cw * 8;
  }
  const bf16* srcB[2];
#pragma unroll
  for (int r = 0; r < 2; r++) {
    int c = r * 512 + tid;
    int row = c >> 3, d = c & 7;
    int cw = d ^ (row & 7);
    srcB[r] = Bt + (size_t)(rowB0 + row) * ldb + cw * 8;
  }

  f32x4 acc[4][4];
#pragma unroll
  for (int i = 0; i < 4; i++)
#pragma unroll
    for (int j = 0; j < 4; j++) acc[i][j] = (f32x4){0.f, 0.f, 0.f, 0.f};

  const int fr = lane & 15;
  const int hi = lane >> 4;
  const int swz = fr & 7;

  auto STAGE = [&](int slot) {
    bf16* dst = lds + slot * TILE;
#pragma unroll
    for (int r = 0; r < 4; r++) {
      load16_lds(srcA[r], dst + (r * 8 + wave) * 512);
      srcA[r] += 64;
    }
#pragma unroll
    for (int r = 0; r < 2; r++) {
      load16_lds(srcB[r], dst + ASZ + (r * 8 + wave) * 512);
      srcB[r] += 64;
    }
  };

  STAGE(0);
  STAGE(1);
  const int nIter = 512 >> 6;  // K = Hd = 512 -> 8 iters
  int cur = 0, stg = 2;
  for (int it = 0; it < nIter; ++it) {
    if (it < nIter - 1)
      asm volatile("s_waitcnt vmcnt(6)" ::: "memory");
    else
      asm volatile("s_waitcnt vmcnt(0)" ::: "memory");
    __builtin_amdgcn_s_barrier();
    __builtin_amdgcn_sched_barrier(0);
    if (it + 2 < nIter) STAGE(stg);
    const bf16* lA = lds + cur * TILE;
    const bf16* lB = lA + ASZ;
#pragma unroll
    for (int ks = 0; ks < 2; ks++) {
      bf16x8 af[4], bfr[4];
#pragma unroll
      for (int f = 0; f < 4; f++) {
        int rowa = wm + f * 16 + fr;
        af[f] = *(const bf16x8*)(lA + rowa * 64 + ((ks * 4 + hi) ^ swz) * 8);
        int rowb = wn + f * 16 + fr;
        bfr[f] = *(const bf16x8*)(lB + rowb * 64 + ((ks * 4 + hi) ^ swz) * 8);
      }
#pragma unroll
      for (int i = 0; i < 4; i++)
#pragma unroll
        for (int j = 0; j < 4; j++)
          acc[i][j] = __builtin_amdgcn_mfma_f32_16x16x32_bf16(af[i], bfr[j], acc[i][j], 0, 0, 0);
    }
    cur = (cur == 2) ? 0 : cur + 1;
    stg = (stg == 2) ? 0 : stg + 1;
  }

  const int orow = hi * 4;
  const int ocol = fr;
#pragma unroll
  for (int i = 0; i < 4; i++) {
#pragma unroll
    for (int j = 0; j < 4; j++) {
      int row0 = rowA0 + wm + i * 16 + orow;
      int col = rowB0 + wn + j * 16 + ocol;
#pragma unroll
      for (int q = 0; q < 4; q++) {
        float v = acc[i][j][q];
        size_t idx = (size_t)(row0 + q) * N + col;
        if constexpr (EPI == 0) {
          outB[idx] = (bf16)gelu_tanh(v + bias[col]);
        } else {
          outF[idx] = v;
        }
      }
    }
  }
}

// ---------- logits GEMM: 256x256 tile, BK=32, 512 thr, 3-slot, XCD swizzle ----------
// 8 waves as 2M x 4N; BK=32 swizzle: LDS[row][d] = global[row][d ^ ((row>>1)&3)].
__global__ __launch_bounds__(512, 1) void gemm_logits(
    const bf16* __restrict__ A, const bf16* __restrict__ Bt,
    float* __restrict__ outF, int M, int N, int lda, int ldb) {
  constexpr int ASZ = 256 * 32;
  constexpr int TILE = 2 * ASZ;    // 32 KB
  __shared__ bf16 lds[3 * TILE];   // 96 KB
  const int tid = threadIdx.x;
  const int wave = tid >> 6;
  const int lane = tid & 63;
  const int wm = (wave >> 2) * 128;  // 0,128
  const int wn = (wave & 3) * 64;    // 0,64,128,192

  // bijective XCD swizzle (gridDim.x = 3152, %8==0), M-panel inner (nM=16, pow2)
  const int per = gridDim.x >> 3;
  const int wg = (blockIdx.x & 7) * per + (blockIdx.x >> 3);
  const int bm = wg & 15;
  const int bn = wg >> 4;
  const int rowA0 = bm * 256;
  const int rowB0 = bn * 256;

  const bf16* srcA[2];
  const bf16* srcB[2];
#pragma unroll
  for (int r = 0; r < 2; r++) {
    int c = r * 512 + tid;  // 1024 chunks over 256x32
    int row = c >> 2, d = c & 3;
    int cw = d ^ ((row >> 1) & 3);
    srcA[r] = A + (size_t)(rowA0 + row) * lda + cw * 8;
    srcB[r] = Bt + (size_t)(rowB0 + row) * ldb + cw * 8;
  }

  f32x4 acc[8][4];
#pragma unroll
  for (int i = 0; i < 8; i++)
#pragma unroll
    for (int j = 0; j < 4; j++) acc[i][j] = (f32x4){0.f, 0.f, 0.f, 0.f};

  const int fr = lane & 15;
  const int hi = lane >> 4;
  const int sw32 = (fr >> 1) & 3;

  auto STAGE = [&](int slot) {
    bf16* dst = lds + slot * TILE;
#pragma unroll
    for (int r = 0; r < 2; r++) {
      load16_lds(srcA[r], dst + (r * 8 + wave) * 512);
      srcA[r] += 32;
      load16_lds(srcB[r], dst + ASZ + (r * 8 + wave) * 512);
      srcB[r] += 32;
    }
  };

  STAGE(0);
  STAGE(1);
  const int nIter = 512 >> 5;  // K = 512
  int cur = 0, stg = 2;
  for (int it = 0; it < nIter; ++it) {
    if (it < nIter - 1)
      asm volatile("s_waitcnt vmcnt(4)" ::: "memory");
    else
      asm volatile("s_waitcnt vmcnt(0)" ::: "memory");
    __builtin_amdgcn_s_barrier();
    __builtin_amdgcn_sched_barrier(0);
    if (it + 2 < nIter) STAGE(stg);
    const bf16* lA = lds + cur * TILE;
    const bf16* lB = lA + ASZ;
    bf16x8 af[8], bfr[4];
#pragma unroll
    for (int f = 0; f < 8; f++) {
      int rowa = wm + f * 16 + fr;
      af[f] = *(const bf16x8*)(lA + rowa * 32 + (hi ^ sw32) * 8);
    }
#pragma unroll
    for (int f = 0; f < 4; f++) {
      int rowb = wn + f * 16 + fr;
      bfr[f] = *(const bf16x8*)(lB + rowb * 32 + (hi ^ sw32) * 8);
    }
#pragma unroll
    for (int i = 0; i < 8; i++)
#pragma unroll
      for (int j = 0; j < 4; j++)
        acc[i][j] = __builtin_amdgcn_mfma_f32_16x16x32_bf16(af[i], bfr[j], acc[i][j], 0, 0, 0);
    cur = (cur == 2) ? 0 : cur + 1;
    stg = (stg == 2) ? 0 : stg + 1;
  }

  const int orow = hi * 4;
  const int ocol = fr;
#pragma unroll
  for (int i = 0; i < 8; i++) {
#pragma unroll
    for (int j = 0; j < 4; j++) {
      int row0 = rowA0 + wm + i * 16 + orow;
      int col = rowB0 + wn + j * 16 + ocol;
      if (col < N) {
#pragma unroll
        for (int q = 0; q < 4; q++)
          outF[(size_t)(row0 + q) * N + col] = acc[i][j][q];
      }
    }
  }
}

// ---------- final hidden: h[:, -1, :] -> out ----------
__global__ void tail_copy(const float* __restrict__ h, float* __restrict__ out) {
  int t = blockIdx.x * 256 + threadIdx.x;  // 0..2047
  int b = t >> 9, k = t & 511;
  out[t] = h[((size_t)(b * 1024 + 1023)) * Hd + k];
}

// ---------- launch ----------
extern "C" void kernel_launch(void* const* d_in, const int* in_sizes, int n_in,
                              void* d_out, int out_size, void* d_ws, size_t ws_size,
                              hipStream_t stream) {
  const int* ids = (const int*)d_in[0];
  const float* emb = (const float*)d_in[1];
  const float* hp_w = (const float*)d_in[2];
  const float* hp_b = (const float*)d_in[3];
  const float* ln_w = (const float*)d_in[4];
  const float* ln_b = (const float*)d_in[5];
  const float* W1 = (const float*)d_in[6];
  const float* b1 = (const float*)d_in[7];
  const float* W2 = (const float*)d_in[8];
  const float* b2 = (const float*)d_in[9];
  const float* lnf_w = (const float*)d_in[10];
  const float* lnf_b = (const float*)d_in[11];
  const float* eow = (const float*)d_in[12];
  float* out = (float*)d_out;

  char* ws = (char*)d_ws;
  float* h = (float*)(ws);                          // 8 MB
  bf16* ybf = (bf16*)(ws + (8u << 20));             // 4 MB
  bf16* abf = (bf16*)(ws + (12u << 20));            // 16 MB
  bf16* W1t = (bf16*)(ws + (28u << 20));            // 12 MB
  bf16* W2t = (bf16*)(ws + (40u << 20));            // 12 MB
  bf16* hpwB = (bf16*)(ws + (52u << 20));           // 0.5 MB
  bf16* eowB = (bf16*)(ws + (53u << 20));           // 51.6 MB (padded to Vpad rows)

  // split-K partials live in d_out's logits region (overwritten by logits GEMM later)
  float* p0 = out;                    // 2M floats
  float* p1 = out + (size_t)Md * Hd;  // next 2M floats

  // weight prep
  {
    int n8cast = Vd * Hd / 8, n8tot = Vpad * Hd / 8;
    cast8pad<<<dim3((n8tot + 255) / 256), dim3(256), 0, stream>>>(eow, eowB, n8cast, n8tot);
  }
  cast8<<<dim3(Hd * Hd / 8 / 256), dim3(256), 0, stream>>>(hp_w, hpwB, Hd * Hd / 8);
  transpose_cast<<<dim3(Fd / 32, Hd / 32, Ld), dim3(32, 8), 0, stream>>>(W1, W1t, Hd, Fd);
  transpose_cast<<<dim3(Hd / 32, Fd / 32, Ld), dim3(32, 8), 0, stream>>>(W2, W2t, Fd, Hd);

  gather_embed<<<dim3(Md), dim3(128), 0, stream>>>(ids, emb, h);

  // one MLP layer: ln (with optional fused finish) -> gemm1(256x128) -> split-K gemm2
  auto layer = [&](int l, int mode, const float* fb, const float* lw, const float* lb) {
    if (mode == 0)
      ln_rows<0><<<dim3(Md / 4), dim3(256), 0, stream>>>(h, p0, p1, fb, lw, lb, h, ybf);
    else if (mode == 1)
      ln_rows<1><<<dim3(Md / 4), dim3(256), 0, stream>>>(h, p0, p1, fb, lw, lb, h, ybf);
    else
      ln_rows<2><<<dim3(Md / 4), dim3(256), 0, stream>>>(h, p0, p1, fb, lw, lb, h, ybf);
    gemm_bt256<0><<<dim3(Fd / 128, Md / 256), dim3(512), 0, stream>>>(
        ybf, W1t + (size_t)l * Fd * Hd, b1 + (size_t)l * Fd, (float*)nullptr, abf,
        Md, Fd, Hd, Hd);
    gemm_bt<4><<<dim3(Hd / 64, Md / 128, 2), dim3(256), 0, stream>>>(
        abf, W2t + (size_t)l * Hd * Fd, (const float*)nullptr, p0, (bf16*)nullptr,
        Md, Hd, Fd / 2, Fd, Fd);
  };

  // ---- stack 1 ----
  layer(0, 0, nullptr, ln_w, ln_b);
  for (int l = 1; l < Ld; l++)
    layer(l, 1, b2 + (size_t)(l - 1) * Hd, ln_w + (size_t)l * Hd, ln_b + (size_t)l * Hd);
  finish2<<<dim3(Md * Hd / 8 / 256), dim3(256), 0, stream>>>(
      p0, p1, b2 + (size_t)(Ld - 1) * Hd, h, ybf);

  // ---- hp projection (split-K=2, finish fused into next LN) ----
  gemm_bt<4><<<dim3(Hd / 64, Md / 128, 2), dim3(256), 0, stream>>>(
      ybf, hpwB, (const float*)nullptr, p0, (bf16*)nullptr, Md, Hd, Hd / 2, Hd, Hd);

  // ---- stack 2 ----
  layer(0, 2, hp_b, ln_w, ln_b);
  for (int l = 1; l < Ld; l++)
    layer(l, 1, b2 + (size_t)(l - 1) * Hd, ln_w + (size_t)l * Hd, ln_b + (size_t)l * Hd);

  // ---- final LN (fused finish of last gemm2) + logits (256x256, XCD swizzle) ----
  ln_rows<1><<<dim3(Md / 4), dim3(256), 0, stream>>>(
      h, p0, p1, b2 + (size_t)(Ld - 1) * Hd, lnf_w, lnf_b, h, ybf);
  gemm_logits<<<dim3((Vpad / 256) * (Md / 256)), dim3(512), 0, stream>>>(
      ybf, eowB, out, Md, Vd, Hd, Hd);

  // final hidden
  tail_copy<<<dim3(8), dim3(256), 0, stream>>>(h, out + (size_t)Md * Vd);
}

// Round 10
// 941.159 us; speedup vs baseline: 1.1015x; 1.1015x over previous
//
#include <hip/hip_runtime.h>
#include <hip/hip_bf16.h>
#include <cstdint>

using bf16 = __hip_bfloat16;
typedef __bf16 bf16x8 __attribute__((ext_vector_type(8)));
typedef float f32x4 __attribute__((ext_vector_type(4)));

constexpr int Hd = 512;
constexpr int Ld = 6;
constexpr int Fd = 2048;
constexpr int Vd = 50304;
constexpr int Vpad = 50432;  // 197*256
constexpr int Md = 4096;     // B*S = 4*1024

// ---------- helpers ----------
__device__ __forceinline__ unsigned short f2b(float x) {
  return __builtin_bit_cast(unsigned short, __float2bfloat16(x));
}

__device__ __forceinline__ float gelu_tanh(float x) {
  const float c = 0.7978845608028654f;  // sqrt(2/pi)
  float x3 = x * x * x;
  return 0.5f * x * (1.0f + tanhf(c * (x + 0.044715f * x3)));
}

__device__ __forceinline__ void load16_lds(const bf16* g, bf16* l) {
  __builtin_amdgcn_global_load_lds(
      (const __attribute__((address_space(1))) void*)g,
      (__attribute__((address_space(3))) void*)l, 16, 0, 0);
}

// ---------- cast fp32 -> bf16 with zero pad tail (for eowB) ----------
__global__ __launch_bounds__(256) void cast8pad(const float* __restrict__ in,
                                                bf16* __restrict__ out, int n8cast,
                                                int n8tot) {
  int i = blockIdx.x * 256 + threadIdx.x;
  if (i >= n8tot) return;
  if (i < n8cast) {
    const float4* p = (const float4*)in;
    float4 a = p[2 * i], b = p[2 * i + 1];
    uint4 o = {(unsigned)f2b(a.x) | ((unsigned)f2b(a.y) << 16),
               (unsigned)f2b(a.z) | ((unsigned)f2b(a.w) << 16),
               (unsigned)f2b(b.x) | ((unsigned)f2b(b.y) << 16),
               (unsigned)f2b(b.z) | ((unsigned)f2b(b.w) << 16)};
    ((uint4*)out)[i] = o;
  } else {
    ((uint4*)out)[i] = uint4{0, 0, 0, 0};
  }
}

// ---------- cast fp32 -> bf16, 8 elems/thread ----------
__global__ __launch_bounds__(256) void cast8(const float* __restrict__ in,
                                             bf16* __restrict__ out, int n8) {
  int i = blockIdx.x * 256 + threadIdx.x;
  if (i >= n8) return;
  const float4* p = (const float4*)in;
  float4 a = p[2 * i], b = p[2 * i + 1];
  uint4 o = {(unsigned)f2b(a.x) | ((unsigned)f2b(a.y) << 16),
             (unsigned)f2b(a.z) | ((unsigned)f2b(a.w) << 16),
             (unsigned)f2b(b.x) | ((unsigned)f2b(b.y) << 16),
             (unsigned)f2b(b.z) | ((unsigned)f2b(b.w) << 16)};
  ((uint4*)out)[i] = o;
}

// ---------- transpose+cast: in (R,C) f32 -> out (C,R) bf16, batched over z ----------
__global__ void transpose_cast(const float* __restrict__ in, bf16* __restrict__ out,
                               int R, int C) {
  __shared__ float tile[32][33];
  int l = blockIdx.z;
  in += (size_t)l * R * C;
  out += (size_t)l * R * C;
  int c0 = blockIdx.x * 32, r0 = blockIdx.y * 32;
#pragma unroll
  for (int i = 0; i < 4; i++) {
    int r = r0 + threadIdx.y + i * 8;
    tile[threadIdx.y + i * 8][threadIdx.x] = in[(size_t)r * C + c0 + threadIdx.x];
  }
  __syncthreads();
#pragma unroll
  for (int i = 0; i < 4; i++) {
    int c = c0 + threadIdx.y + i * 8;
    out[(size_t)c * R + r0 + threadIdx.x] = (bf16)tile[threadIdx.x][threadIdx.y + i * 8];
  }
}

// ---------- embedding gather ----------
__global__ void gather_embed(const int* __restrict__ ids, const float* __restrict__ emb,
                             float* __restrict__ h) {
  int row = blockIdx.x;
  int id = ids[row];
  const float4* src = (const float4*)(emb + (size_t)id * Hd);
  float4* dst = (float4*)(h + (size_t)row * Hd);
  dst[threadIdx.x] = src[threadIdx.x];
}

// ---------- layernorm, one wave per row, with fused split-K reduce ----------
// MODE 0: x = h[row]                         (plain LN)
// MODE 1: x = h + fb[col] + p0 + p1; h = x   (finish gemm2 split-K + residual)
// MODE 2: x = p0 + p1 + fb[col];    h = x    (finish hp split-K, overwrite)
template <int MODE>
__global__ __launch_bounds__(256) void ln_rows(
    const float* __restrict__ h, const float* __restrict__ p0,
    const float* __restrict__ p1, const float* __restrict__ fb,
    const float* __restrict__ w, const float* __restrict__ b,
    float* __restrict__ hout, bf16* __restrict__ y) {
  int row = blockIdx.x * 4 + (threadIdx.x >> 6);
  int lane = threadIdx.x & 63;
  size_t base = (size_t)row * Hd + lane * 8;
  float xv[8];
  if constexpr (MODE == 0) {
    *(float4*)&xv[0] = *(const float4*)(h + base);
    *(float4*)&xv[4] = *(const float4*)(h + base + 4);
  } else {
    float4 q0 = *(const float4*)(p0 + base), q1 = *(const float4*)(p0 + base + 4);
    float4 r0 = *(const float4*)(p1 + base), r1 = *(const float4*)(p1 + base + 4);
    float4 f0 = *(const float4*)(fb + lane * 8), f1 = *(const float4*)(fb + lane * 8 + 4);
    xv[0] = q0.x + r0.x + f0.x; xv[1] = q0.y + r0.y + f0.y;
    xv[2] = q0.z + r0.z + f0.z; xv[3] = q0.w + r0.w + f0.w;
    xv[4] = q1.x + r1.x + f1.x; xv[5] = q1.y + r1.y + f1.y;
    xv[6] = q1.z + r1.z + f1.z; xv[7] = q1.w + r1.w + f1.w;
    if constexpr (MODE == 1) {
      float4 a0 = *(const float4*)(h + base), a1 = *(const float4*)(h + base + 4);
      xv[0] += a0.x; xv[1] += a0.y; xv[2] += a0.z; xv[3] += a0.w;
      xv[4] += a1.x; xv[5] += a1.y; xv[6] += a1.z; xv[7] += a1.w;
    }
    *(float4*)(hout + base) = make_float4(xv[0], xv[1], xv[2], xv[3]);
    *(float4*)(hout + base + 4) = make_float4(xv[4], xv[5], xv[6], xv[7]);
  }
  float s = 0.f;
#pragma unroll
  for (int j = 0; j < 8; j++) s += xv[j];
#pragma unroll
  for (int off = 1; off < 64; off <<= 1) s += __shfl_xor(s, off);
  float mu = s * (1.0f / 512.0f);
  float s2 = 0.f;
#pragma unroll
  for (int j = 0; j < 8; j++) {
    xv[j] -= mu;
    s2 += xv[j] * xv[j];
  }
#pragma unroll
  for (int off = 1; off < 64; off <<= 1) s2 += __shfl_xor(s2, off);
  float scale = rsqrtf(s2 * (1.0f / 512.0f) + 1e-5f);
  float o[8];
#pragma unroll
  for (int j = 0; j < 8; j++) {
    float wj = w[lane * 8 + j], bj = b[lane * 8 + j];
    o[j] = xv[j] * scale * wj + bj;
  }
  uint4 pk = {(unsigned)f2b(o[0]) | ((unsigned)f2b(o[1]) << 16),
              (unsigned)f2b(o[2]) | ((unsigned)f2b(o[3]) << 16),
              (unsigned)f2b(o[4]) | ((unsigned)f2b(o[5]) << 16),
              (unsigned)f2b(o[6]) | ((unsigned)f2b(o[7]) << 16)};
  *(uint4*)(y + base) = pk;
}

// ---------- finish split-K gemm2 of stack1: h += fb + p0 + p1, also emit bf16 ----------
__global__ __launch_bounds__(256) void finish2(
    const float* __restrict__ p0, const float* __restrict__ p1,
    const float* __restrict__ fb, float* __restrict__ h, bf16* __restrict__ hbf) {
  int i = blockIdx.x * 256 + threadIdx.x;  // 8 elems each; grid covers 2M elems
  size_t base = (size_t)i * 8;
  int col = (int)(base & 511);
  float x[8];
#pragma unroll
  for (int j = 0; j < 8; j += 4) {
    float4 a = *(const float4*)(h + base + j);
    float4 q = *(const float4*)(p0 + base + j);
    float4 r = *(const float4*)(p1 + base + j);
    float4 f = *(const float4*)(fb + col + j);
    x[j] = a.x + q.x + r.x + f.x; x[j + 1] = a.y + q.y + r.y + f.y;
    x[j + 2] = a.z + q.z + r.z + f.z; x[j + 3] = a.w + q.w + r.w + f.w;
    *(float4*)(h + base + j) = make_float4(x[j], x[j + 1], x[j + 2], x[j + 3]);
  }
  uint4 pk = {(unsigned)f2b(x[0]) | ((unsigned)f2b(x[1]) << 16),
              (unsigned)f2b(x[2]) | ((unsigned)f2b(x[3]) << 16),
              (unsigned)f2b(x[4]) | ((unsigned)f2b(x[5]) << 16),
              (unsigned)f2b(x[6]) | ((unsigned)f2b(x[7]) << 16)};
  *(uint4*)(hbf + base) = pk;
}

// ============ GEMM kernels: BK=64, conflict-free XOR swizzle ============
// LDS layout per operand tile: rows of 64 bf16 (128B) = 8 chunks of 16B.
// Swizzle (both sides): LDS[row][d] holds global[row][d ^ (row&7)].

// ---------- GEMM 128x128 tile, BK=64, 256 thr, 3-slot counted-vmcnt ----------
// (round-8 proven config)
// EPI 0: out_bf16 = gelu(acc + bias)
// EPI 4: out_f32[z*M*N + idx] = acc   (split-K partial)
template <int EPI>
__global__ __launch_bounds__(256) void gemm_bt(
    const bf16* __restrict__ A, const bf16* __restrict__ Bt,
    const float* __restrict__ bias, float* __restrict__ outF,
    bf16* __restrict__ outB, int M, int N, int Klen, int lda, int ldb) {
  constexpr int ASZ = 128 * 64;          // 8192 elems
  constexpr int TILE = 2 * ASZ;          // A + B = 32 KB
  __shared__ bf16 lds[3 * TILE];         // 96 KB
  const int tid = threadIdx.x;
  const int wave = tid >> 6;
  const int lane = tid & 63;
  const int wm = (wave >> 1) * 64;
  const int wn = (wave & 1) * 64;

  const int bn = blockIdx.x;
  const int bm = blockIdx.y;
  const int rowA0 = bm * 128;
  const int rowB0 = bn * 128;
  const int k0 = blockIdx.z * Klen;

  const bf16* srcA[4];
  const bf16* srcB[4];
#pragma unroll
  for (int r = 0; r < 4; r++) {
    int c = r * 256 + tid;
    int row = c >> 3, d = c & 7;
    int cw = d ^ (row & 7);
    srcA[r] = A + (size_t)(rowA0 + row) * lda + k0 + cw * 8;
    srcB[r] = Bt + (size_t)(rowB0 + row) * ldb + k0 + cw * 8;
  }

  f32x4 acc[4][4];
#pragma unroll
  for (int i = 0; i < 4; i++)
#pragma unroll
    for (int j = 0; j < 4; j++) acc[i][j] = (f32x4){0.f, 0.f, 0.f, 0.f};

  const int fr = lane & 15;
  const int hi = lane >> 4;
  const int swz = fr & 7;

  auto STAGE = [&](int slot) {
    bf16* dst = lds + slot * TILE;
#pragma unroll
    for (int r = 0; r < 4; r++) {
      load16_lds(srcA[r], dst + (r * 4 + wave) * 512);
      srcA[r] += 64;
      load16_lds(srcB[r], dst + ASZ + (r * 4 + wave) * 512);
      srcB[r] += 64;
    }
  };

  STAGE(0);
  STAGE(1);
  const int nIter = Klen >> 6;
  int cur = 0, stg = 2;
  for (int it = 0; it < nIter; ++it) {
    if (it < nIter - 1)
      asm volatile("s_waitcnt vmcnt(8)" ::: "memory");
    else
      asm volatile("s_waitcnt vmcnt(0)" ::: "memory");
    __builtin_amdgcn_s_barrier();
    __builtin_amdgcn_sched_barrier(0);
    if (it + 2 < nIter) STAGE(stg);
    const bf16* lA = lds + cur * TILE;
    const bf16* lB = lA + ASZ;
#pragma unroll
    for (int ks = 0; ks < 2; ks++) {
      bf16x8 af[4], bfr[4];
#pragma unroll
      for (int f = 0; f < 4; f++) {
        int rowa = wm + f * 16 + fr;
        af[f] = *(const bf16x8*)(lA + rowa * 64 + ((ks * 4 + hi) ^ swz) * 8);
        int rowb = wn + f * 16 + fr;
        bfr[f] = *(const bf16x8*)(lB + rowb * 64 + ((ks * 4 + hi) ^ swz) * 8);
      }
#pragma unroll
      for (int i = 0; i < 4; i++)
#pragma unroll
        for (int j = 0; j < 4; j++)
          acc[i][j] = __builtin_amdgcn_mfma_f32_16x16x32_bf16(af[i], bfr[j], acc[i][j], 0, 0, 0);
    }
    cur = (cur == 2) ? 0 : cur + 1;
    stg = (stg == 2) ? 0 : stg + 1;
  }

  if constexpr (EPI == 4) outF += (size_t)blockIdx.z * M * N;
  const int orow = hi * 4;
  const int ocol = fr;
#pragma unroll
  for (int i = 0; i < 4; i++) {
#pragma unroll
    for (int j = 0; j < 4; j++) {
      int row0 = rowA0 + wm + i * 16 + orow;
      int col = rowB0 + wn + j * 16 + ocol;
#pragma unroll
      for (int q = 0; q < 4; q++) {
        float v = acc[i][j][q];
        size_t idx = (size_t)(row0 + q) * N + col;
        if constexpr (EPI == 0) {
          outB[idx] = (bf16)gelu_tanh(v + bias[col]);
        } else {
          outF[idx] = v;
        }
      }
    }
  }
}

// ---------- GEMM 256x128 tile, BK=64, 512 thr, 3-slot counted-vmcnt (gemm1) ----------
// 8 waves as 4M x 2N. Loads/thread/STAGE: A 4 + B 2 = 6.
template <int EPI>
__global__ __launch_bounds__(512) void gemm_bt256(
    const bf16* __restrict__ A, const bf16* __restrict__ Bt,
    const float* __restrict__ bias, float* __restrict__ outF,
    bf16* __restrict__ outB, int M, int N, int lda, int ldb) {
  constexpr int ASZ = 256 * 64;          // 16384 elems (32 KB)
  constexpr int BSZ = 128 * 64;          // 8192 elems (16 KB)
  constexpr int TILE = ASZ + BSZ;        // 48 KB
  __shared__ bf16 lds[3 * TILE];         // 144 KB
  const int tid = threadIdx.x;
  const int wave = tid >> 6;
  const int lane = tid & 63;
  const int wm = (wave >> 1) * 64;
  const int wn = (wave & 1) * 64;

  const int bn = blockIdx.x;
  const int bm = blockIdx.y;
  const int rowA0 = bm * 256;
  const int rowB0 = bn * 128;

  const bf16* srcA[4];
#pragma unroll
  for (int r = 0; r < 4; r++) {
    int c = r * 512 + tid;
    int row = c >> 3, d = c & 7;
    int cw = d ^ (row & 7);
    srcA[r] = A + (size_t)(rowA0 + row) * lda + cw * 8;
  }
  const bf16* srcB[2];
#pragma unroll
  for (int r = 0; r < 2; r++) {
    int c = r * 512 + tid;
    int row = c >> 3, d = c & 7;
    int cw = d ^ (row & 7);
    srcB[r] = Bt + (size_t)(rowB0 + row) * ldb + cw * 8;
  }

  f32x4 acc[4][4];
#pragma unroll
  for (int i = 0; i < 4; i++)
#pragma unroll
    for (int j = 0; j < 4; j++) acc[i][j] = (f32x4){0.f, 0.f, 0.f, 0.f};

  const int fr = lane & 15;
  const int hi = lane >> 4;
  const int swz = fr & 7;

  auto STAGE = [&](int slot) {
    bf16* dst = lds + slot * TILE;
#pragma unroll
    for (int r = 0; r < 4; r++) {
      load16_lds(srcA[r], dst + (r * 8 + wave) * 512);
      srcA[r] += 64;
    }
#pragma unroll
    for (int r = 0; r < 2; r++) {
      load16_lds(srcB[r], dst + ASZ + (r * 8 + wave) * 512);
      srcB[r] += 64;
    }
  };

  STAGE(0);
  STAGE(1);
  const int nIter = 512 >> 6;  // K = Hd = 512 -> 8 iters
  int cur = 0, stg = 2;
  for (int it = 0; it < nIter; ++it) {
    if (it < nIter - 1)
      asm volatile("s_waitcnt vmcnt(6)" ::: "memory");
    else
      asm volatile("s_waitcnt vmcnt(0)" ::: "memory");
    __builtin_amdgcn_s_barrier();
    __builtin_amdgcn_sched_barrier(0);
    if (it + 2 < nIter) STAGE(stg);
    const bf16* lA = lds + cur * TILE;
    const bf16* lB = lA + ASZ;
#pragma unroll
    for (int ks = 0; ks < 2; ks++) {
      bf16x8 af[4], bfr[4];
#pragma unroll
      for (int f = 0; f < 4; f++) {
        int rowa = wm + f * 16 + fr;
        af[f] = *(const bf16x8*)(lA + rowa * 64 + ((ks * 4 + hi) ^ swz) * 8);
        int rowb = wn + f * 16 + fr;
        bfr[f] = *(const bf16x8*)(lB + rowb * 64 + ((ks * 4 + hi) ^ swz) * 8);
      }
#pragma unroll
      for (int i = 0; i < 4; i++)
#pragma unroll
        for (int j = 0; j < 4; j++)
          acc[i][j] = __builtin_amdgcn_mfma_f32_16x16x32_bf16(af[i], bfr[j], acc[i][j], 0, 0, 0);
    }
    cur = (cur == 2) ? 0 : cur + 1;
    stg = (stg == 2) ? 0 : stg + 1;
  }

  const int orow = hi * 4;
  const int ocol = fr;
#pragma unroll
  for (int i = 0; i < 4; i++) {
#pragma unroll
    for (int j = 0; j < 4; j++) {
      int row0 = rowA0 + wm + i * 16 + orow;
      int col = rowB0 + wn + j * 16 + ocol;
#pragma unroll
      for (int q = 0; q < 4; q++) {
        float v = acc[i][j][q];
        size_t idx = (size_t)(row0 + q) * N + col;
        if constexpr (EPI == 0) {
          outB[idx] = (bf16)gelu_tanh(v + bias[col]);
        } else {
          outF[idx] = v;
        }
      }
    }
  }
}

// ---------- logits GEMM: 256x256 tile, BK=64, 512 thr, 2-slot 2-barrier ----------
// 8 waves as 2M x 4N (wave 128x64, 64 MFMA/K-step). Counted vmcnt(8): next tile's
// 8 loads stay in flight across the phase. End-barrier protects slot overwrite
// (reads are lgkm-consumed before MFMA, so consumed before the barrier).
__global__ __launch_bounds__(512, 1) void gemm_logits(
    const bf16* __restrict__ A, const bf16* __restrict__ Bt,
    float* __restrict__ outF, int M, int N, int lda, int ldb) {
  constexpr int ASZ = 256 * 64;     // 16384 elems (32 KB)
  constexpr int TILE = 2 * ASZ;     // A + B = 64 KB
  __shared__ bf16 lds[2 * TILE];    // 128 KB
  const int tid = threadIdx.x;
  const int wave = tid >> 6;
  const int lane = tid & 63;
  const int wm = (wave >> 2) * 128;  // 0,128
  const int wn = (wave & 3) * 64;    // 0,64,128,192

  // bijective XCD swizzle (gridDim.x = 3152, %8==0), M-panel inner (nM=16, pow2)
  const int per = gridDim.x >> 3;
  const int wg = (blockIdx.x & 7) * per + (blockIdx.x >> 3);
  const int bm = wg & 15;
  const int bn = wg >> 4;
  const int rowA0 = bm * 256;
  const int rowB0 = bn * 256;

  const bf16* srcA[4];
  const bf16* srcB[4];
#pragma unroll
  for (int r = 0; r < 4; r++) {
    int c = r * 512 + tid;  // 2048 chunks over 256x64
    int row = c >> 3, d = c & 7;
    int cw = d ^ (row & 7);
    srcA[r] = A + (size_t)(rowA0 + row) * lda + cw * 8;
    srcB[r] = Bt + (size_t)(rowB0 + row) * ldb + cw * 8;
  }

  f32x4 acc[8][4];
#pragma unroll
  for (int i = 0; i < 8; i++)
#pragma unroll
    for (int j = 0; j < 4; j++) acc[i][j] = (f32x4){0.f, 0.f, 0.f, 0.f};

  const int fr = lane & 15;
  const int hi = lane >> 4;
  const int swz = fr & 7;

  auto STAGE = [&](int slot) {
    bf16* dst = lds + slot * TILE;
#pragma unroll
    for (int r = 0; r < 4; r++) {
      load16_lds(srcA[r], dst + (r * 8 + wave) * 512);
      srcA[r] += 64;
      load16_lds(srcB[r], dst + ASZ + (r * 8 + wave) * 512);
      srcB[r] += 64;
    }
  };

  STAGE(0);
  const int nIter = 512 >> 6;  // 8 iters
  for (int it = 0; it < nIter; ++it) {
    const int cur = it & 1;
    if (it + 1 < nIter) STAGE(cur ^ 1);  // issue next-tile loads (stay in flight)
    if (it + 1 < nIter)
      asm volatile("s_waitcnt vmcnt(8)" ::: "memory");  // drain cur's 8 only
    else
      asm volatile("s_waitcnt vmcnt(0)" ::: "memory");
    __builtin_amdgcn_s_barrier();
    __builtin_amdgcn_sched_barrier(0);
    const bf16* lA = lds + cur * TILE;
    const bf16* lB = lA + ASZ;
#pragma unroll
    for (int ks = 0; ks < 2; ks++) {
      bf16x8 af[8], bfr[4];
#pragma unroll
      for (int f = 0; f < 8; f++) {
        int rowa = wm + f * 16 + fr;
        af[f] = *(const bf16x8*)(lA + rowa * 64 + ((ks * 4 + hi) ^ swz) * 8);
      }
#pragma unroll
      for (int f = 0; f < 4; f++) {
        int rowb = wn + f * 16 + fr;
        bfr[f] = *(const bf16x8*)(lB + rowb * 64 + ((ks * 4 + hi) ^ swz) * 8);
      }
#pragma unroll
      for (int i = 0; i < 8; i++)
#pragma unroll
        for (int j = 0; j < 4; j++)
          acc[i][j] = __builtin_amdgcn_mfma_f32_16x16x32_bf16(af[i], bfr[j], acc[i][j], 0, 0, 0);
    }
    __builtin_amdgcn_s_barrier();  // all waves done reading cur before overwrite
  }

  const int orow = hi * 4;
  const int ocol = fr;
#pragma unroll
  for (int i = 0; i < 8; i++) {
#pragma unroll
    for (int j = 0; j < 4; j++) {
      int row0 = rowA0 + wm + i * 16 + orow;
      int col = rowB0 + wn + j * 16 + ocol;
      if (col < N) {
#pragma unroll
        for (int q = 0; q < 4; q++)
          outF[(size_t)(row0 + q) * N + col] = acc[i][j][q];
      }
    }
  }
}

// ---------- final hidden: h[:, -1, :] -> out ----------
__global__ void tail_copy(const float* __restrict__ h, float* __restrict__ out) {
  int t = blockIdx.x * 256 + threadIdx.x;  // 0..2047
  int b = t >> 9, k = t & 511;
  out[t] = h[((size_t)(b * 1024 + 1023)) * Hd + k];
}

// ---------- launch ----------
extern "C" void kernel_launch(void* const* d_in, const int* in_sizes, int n_in,
                              void* d_out, int out_size, void* d_ws, size_t ws_size,
                              hipStream_t stream) {
  const int* ids = (const int*)d_in[0];
  const float* emb = (const float*)d_in[1];
  const float* hp_w = (const float*)d_in[2];
  const float* hp_b = (const float*)d_in[3];
  const float* ln_w = (const float*)d_in[4];
  const float* ln_b = (const float*)d_in[5];
  const float* W1 = (const float*)d_in[6];
  const float* b1 = (const float*)d_in[7];
  const float* W2 = (const float*)d_in[8];
  const float* b2 = (const float*)d_in[9];
  const float* lnf_w = (const float*)d_in[10];
  const float* lnf_b = (const float*)d_in[11];
  const float* eow = (const float*)d_in[12];
  float* out = (float*)d_out;

  char* ws = (char*)d_ws;
  float* h = (float*)(ws);                          // 8 MB
  bf16* ybf = (bf16*)(ws + (8u << 20));             // 4 MB
  bf16* abf = (bf16*)(ws + (12u << 20));            // 16 MB
  bf16* W1t = (bf16*)(ws + (28u << 20));            // 12 MB
  bf16* W2t = (bf16*)(ws + (40u << 20));            // 12 MB
  bf16* hpwB = (bf16*)(ws + (52u << 20));           // 0.5 MB
  bf16* eowB = (bf16*)(ws + (53u << 20));           // 51.6 MB (padded to Vpad rows)

  // split-K partials live in d_out's logits region (overwritten by logits GEMM later)
  float* p0 = out;                    // 2M floats
  float* p1 = out + (size_t)Md * Hd;  // next 2M floats

  // weight prep
  {
    int n8cast = Vd * Hd / 8, n8tot = Vpad * Hd / 8;
    cast8pad<<<dim3((n8tot + 255) / 256), dim3(256), 0, stream>>>(eow, eowB, n8cast, n8tot);
  }
  cast8<<<dim3(Hd * Hd / 8 / 256), dim3(256), 0, stream>>>(hp_w, hpwB, Hd * Hd / 8);
  transpose_cast<<<dim3(Fd / 32, Hd / 32, Ld), dim3(32, 8), 0, stream>>>(W1, W1t, Hd, Fd);
  transpose_cast<<<dim3(Hd / 32, Fd / 32, Ld), dim3(32, 8), 0, stream>>>(W2, W2t, Fd, Hd);

  gather_embed<<<dim3(Md), dim3(128), 0, stream>>>(ids, emb, h);

  // one MLP layer: ln (with optional fused finish) -> gemm1(256x128) -> split-K gemm2
  auto layer = [&](int l, int mode, const float* fb, const float* lw, const float* lb) {
    if (mode == 0)
      ln_rows<0><<<dim3(Md / 4), dim3(256), 0, stream>>>(h, p0, p1, fb, lw, lb, h, ybf);
    else if (mode == 1)
      ln_rows<1><<<dim3(Md / 4), dim3(256), 0, stream>>>(h, p0, p1, fb, lw, lb, h, ybf);
    else
      ln_rows<2><<<dim3(Md / 4), dim3(256), 0, stream>>>(h, p0, p1, fb, lw, lb, h, ybf);
    gemm_bt256<0><<<dim3(Fd / 128, Md / 256), dim3(512), 0, stream>>>(
        ybf, W1t + (size_t)l * Fd * Hd, b1 + (size_t)l * Fd, (float*)nullptr, abf,
        Md, Fd, Hd, Hd);
    gemm_bt<4><<<dim3(Hd / 128, Md / 128, 2), dim3(256), 0, stream>>>(
        abf, W2t + (size_t)l * Hd * Fd, (const float*)nullptr, p0, (bf16*)nullptr,
        Md, Hd, Fd / 2, Fd, Fd);
  };

  // ---- stack 1 ----
  layer(0, 0, nullptr, ln_w, ln_b);
  for (int l = 1; l < Ld; l++)
    layer(l, 1, b2 + (size_t)(l - 1) * Hd, ln_w + (size_t)l * Hd, ln_b + (size_t)l * Hd);
  finish2<<<dim3(Md * Hd / 8 / 256), dim3(256), 0, stream>>>(
      p0, p1, b2 + (size_t)(Ld - 1) * Hd, h, ybf);

  // ---- hp projection (split-K=2, finish fused into next LN) ----
  gemm_bt<4><<<dim3(Hd / 128, Md / 128, 2), dim3(256), 0, stream>>>(
      ybf, hpwB, (const float*)nullptr, p0, (bf16*)nullptr, Md, Hd, Hd / 2, Hd, Hd);

  // ---- stack 2 ----
  layer(0, 2, hp_b, ln_w, ln_b);
  for (int l = 1; l < Ld; l++)
    layer(l, 1, b2 + (size_t)(l - 1) * Hd, ln_w + (size_t)l * Hd, ln_b + (size_t)l * Hd);

  // ---- final LN (fused finish of last gemm2) + logits (256x256 BK=64, XCD swizzle) ----
  ln_rows<1><<<dim3(Md / 4), dim3(256), 0, stream>>>(
      h, p0, p1, b2 + (size_t)(Ld - 1) * Hd, lnf_w, lnf_b, h, ybf);
  gemm_logits<<<dim3((Vpad / 256) * (Md / 256)), dim3(512), 0, stream>>>(
      ybf, eowB, out, Md, Vd, Hd, Hd);

  // final hidden
  tail_copy<<<dim3(8), dim3(256), 0, stream>>>(h, out + (size_t)Md * Vd);
}

// Round 11
// 930.228 us; speedup vs baseline: 1.1145x; 1.0118x over previous
//
#include <hip/hip_runtime.h>
#include <hip/hip_bf16.h>
#include <cstdint>

using bf16 = __hip_bfloat16;
typedef __bf16 bf16x8 __attribute__((ext_vector_type(8)));
typedef float f32x4 __attribute__((ext_vector_type(4)));

constexpr int Hd = 512;
constexpr int Ld = 6;
constexpr int Fd = 2048;
constexpr int Vd = 50304;
constexpr int Vpad = 50432;  // 197*256
constexpr int Md = 4096;     // B*S = 4*1024

// ---------- helpers ----------
__device__ __forceinline__ unsigned short f2b(float x) {
  return __builtin_bit_cast(unsigned short, __float2bfloat16(x));
}

__device__ __forceinline__ float gelu_tanh(float x) {
  const float c = 0.7978845608028654f;  // sqrt(2/pi)
  float x3 = x * x * x;
  return 0.5f * x * (1.0f + tanhf(c * (x + 0.044715f * x3)));
}

__device__ __forceinline__ void load16_lds(const bf16* g, bf16* l) {
  __builtin_amdgcn_global_load_lds(
      (const __attribute__((address_space(1))) void*)g,
      (__attribute__((address_space(3))) void*)l, 16, 0, 0);
}

// ---------- combined weight cast: hp (n8hp) then eow+pad (n8cast/n8tot) ----------
__global__ __launch_bounds__(256) void cast_weights(
    const float* __restrict__ hp, bf16* __restrict__ hpB, int n8hp,
    const float* __restrict__ eow, bf16* __restrict__ eowB, int n8cast, int n8tot) {
  int i = blockIdx.x * 256 + threadIdx.x;
  if (i < n8hp) {
    const float4* p = (const float4*)hp;
    float4 a = p[2 * i], b = p[2 * i + 1];
    uint4 o = {(unsigned)f2b(a.x) | ((unsigned)f2b(a.y) << 16),
               (unsigned)f2b(a.z) | ((unsigned)f2b(a.w) << 16),
               (unsigned)f2b(b.x) | ((unsigned)f2b(b.y) << 16),
               (unsigned)f2b(b.z) | ((unsigned)f2b(b.w) << 16)};
    ((uint4*)hpB)[i] = o;
    return;
  }
  int j = i - n8hp;
  if (j >= n8tot) return;
  if (j < n8cast) {
    const float4* p = (const float4*)eow;
    float4 a = p[2 * j], b = p[2 * j + 1];
    uint4 o = {(unsigned)f2b(a.x) | ((unsigned)f2b(a.y) << 16),
               (unsigned)f2b(a.z) | ((unsigned)f2b(a.w) << 16),
               (unsigned)f2b(b.x) | ((unsigned)f2b(b.y) << 16),
               (unsigned)f2b(b.z) | ((unsigned)f2b(b.w) << 16)};
    ((uint4*)eowB)[j] = o;
  } else {
    ((uint4*)eowB)[j] = uint4{0, 0, 0, 0};
  }
}

// ---------- combined transpose+cast for W1 (z<6: R=Hd,C=Fd) and W2 (z>=6: R=Fd,C=Hd) ----------
__global__ void transpose_cast2(const float* __restrict__ W1, bf16* __restrict__ W1t,
                                const float* __restrict__ W2, bf16* __restrict__ W2t) {
  __shared__ float tile[32][33];
  const int z = blockIdx.z;
  const bool isW1 = z < Ld;
  const int layer = isW1 ? z : z - Ld;
  const int R = isW1 ? Hd : Fd;
  const int C = isW1 ? Fd : Hd;
  const float* in = (isW1 ? W1 : W2) + (size_t)layer * R * C;
  bf16* out = (isW1 ? W1t : W2t) + (size_t)layer * R * C;
  const int tilesX = C >> 5;
  const int bx = blockIdx.x % tilesX;
  const int by = blockIdx.x / tilesX;
  int c0 = bx * 32, r0 = by * 32;
#pragma unroll
  for (int i = 0; i < 4; i++) {
    int r = r0 + threadIdx.y + i * 8;
    tile[threadIdx.y + i * 8][threadIdx.x] = in[(size_t)r * C + c0 + threadIdx.x];
  }
  __syncthreads();
#pragma unroll
  for (int i = 0; i < 4; i++) {
    int c = c0 + threadIdx.y + i * 8;
    out[(size_t)c * R + r0 + threadIdx.x] = (bf16)tile[threadIdx.x][threadIdx.y + i * 8];
  }
}

// ---------- layernorm, one wave per row, with fused split-K reduce / gather / tail ----------
// MODE 0: x = h[row]                          (plain LN)
// MODE 1: x = h + fb[col] + p0 + p1; h = x    (finish gemm2 split-K + residual)
// MODE 2: x = p0 + p1 + fb[col];     h = x    (finish hp split-K, overwrite)
// MODE 3: x = emb[ids[row]];         h = x    (fused embedding gather + LN)
// MODE 4: MODE 1 + tail: rows with (row&1023)==1023 also write x to out2[b*Hd..]
template <int MODE>
__global__ __launch_bounds__(256) void ln_rows(
    const float* __restrict__ h, const float* __restrict__ p0,
    const float* __restrict__ p1, const float* __restrict__ fb,
    const float* __restrict__ w, const float* __restrict__ b,
    float* __restrict__ hout, bf16* __restrict__ y,
    const int* __restrict__ ids, const float* __restrict__ emb,
    float* __restrict__ out2) {
  int row = blockIdx.x * 4 + (threadIdx.x >> 6);
  int lane = threadIdx.x & 63;
  size_t base = (size_t)row * Hd + lane * 8;
  float xv[8];
  if constexpr (MODE == 0) {
    *(float4*)&xv[0] = *(const float4*)(h + base);
    *(float4*)&xv[4] = *(const float4*)(h + base + 4);
  } else if constexpr (MODE == 3) {
    int id = ids[row];
    const float* src = emb + (size_t)id * Hd + lane * 8;
    *(float4*)&xv[0] = *(const float4*)(src);
    *(float4*)&xv[4] = *(const float4*)(src + 4);
    *(float4*)(hout + base) = make_float4(xv[0], xv[1], xv[2], xv[3]);
    *(float4*)(hout + base + 4) = make_float4(xv[4], xv[5], xv[6], xv[7]);
  } else {
    float4 q0 = *(const float4*)(p0 + base), q1 = *(const float4*)(p0 + base + 4);
    float4 r0 = *(const float4*)(p1 + base), r1 = *(const float4*)(p1 + base + 4);
    float4 f0 = *(const float4*)(fb + lane * 8), f1 = *(const float4*)(fb + lane * 8 + 4);
    xv[0] = q0.x + r0.x + f0.x; xv[1] = q0.y + r0.y + f0.y;
    xv[2] = q0.z + r0.z + f0.z; xv[3] = q0.w + r0.w + f0.w;
    xv[4] = q1.x + r1.x + f1.x; xv[5] = q1.y + r1.y + f1.y;
    xv[6] = q1.z + r1.z + f1.z; xv[7] = q1.w + r1.w + f1.w;
    if constexpr (MODE == 1 || MODE == 4) {
      float4 a0 = *(const float4*)(h + base), a1 = *(const float4*)(h + base + 4);
      xv[0] += a0.x; xv[1] += a0.y; xv[2] += a0.z; xv[3] += a0.w;
      xv[4] += a1.x; xv[5] += a1.y; xv[6] += a1.z; xv[7] += a1.w;
    }
    *(float4*)(hout + base) = make_float4(xv[0], xv[1], xv[2], xv[3]);
    *(float4*)(hout + base + 4) = make_float4(xv[4], xv[5], xv[6], xv[7]);
    if constexpr (MODE == 4) {
      if ((row & 1023) == 1023) {
        int bb = row >> 10;
        float* dst = out2 + (size_t)bb * Hd + lane * 8;
        *(float4*)(dst) = make_float4(xv[0], xv[1], xv[2], xv[3]);
        *(float4*)(dst + 4) = make_float4(xv[4], xv[5], xv[6], xv[7]);
      }
    }
  }
  float s = 0.f;
#pragma unroll
  for (int j = 0; j < 8; j++) s += xv[j];
#pragma unroll
  for (int off = 1; off < 64; off <<= 1) s += __shfl_xor(s, off);
  float mu = s * (1.0f / 512.0f);
  float s2 = 0.f;
#pragma unroll
  for (int j = 0; j < 8; j++) {
    xv[j] -= mu;
    s2 += xv[j] * xv[j];
  }
#pragma unroll
  for (int off = 1; off < 64; off <<= 1) s2 += __shfl_xor(s2, off);
  float scale = rsqrtf(s2 * (1.0f / 512.0f) + 1e-5f);
  float o[8];
#pragma unroll
  for (int j = 0; j < 8; j++) {
    float wj = w[lane * 8 + j], bj = b[lane * 8 + j];
    o[j] = xv[j] * scale * wj + bj;
  }
  uint4 pk = {(unsigned)f2b(o[0]) | ((unsigned)f2b(o[1]) << 16),
              (unsigned)f2b(o[2]) | ((unsigned)f2b(o[3]) << 16),
              (unsigned)f2b(o[4]) | ((unsigned)f2b(o[5]) << 16),
              (unsigned)f2b(o[6]) | ((unsigned)f2b(o[7]) << 16)};
  *(uint4*)(y + base) = pk;
}

// ---------- finish split-K gemm2 of stack1: h += fb + p0 + p1, also emit bf16 ----------
__global__ __launch_bounds__(256) void finish2(
    const float* __restrict__ p0, const float* __restrict__ p1,
    const float* __restrict__ fb, float* __restrict__ h, bf16* __restrict__ hbf) {
  int i = blockIdx.x * 256 + threadIdx.x;  // 8 elems each; grid covers 2M elems
  size_t base = (size_t)i * 8;
  int col = (int)(base & 511);
  float x[8];
#pragma unroll
  for (int j = 0; j < 8; j += 4) {
    float4 a = *(const float4*)(h + base + j);
    float4 q = *(const float4*)(p0 + base + j);
    float4 r = *(const float4*)(p1 + base + j);
    float4 f = *(const float4*)(fb + col + j);
    x[j] = a.x + q.x + r.x + f.x; x[j + 1] = a.y + q.y + r.y + f.y;
    x[j + 2] = a.z + q.z + r.z + f.z; x[j + 3] = a.w + q.w + r.w + f.w;
    *(float4*)(h + base + j) = make_float4(x[j], x[j + 1], x[j + 2], x[j + 3]);
  }
  uint4 pk = {(unsigned)f2b(x[0]) | ((unsigned)f2b(x[1]) << 16),
              (unsigned)f2b(x[2]) | ((unsigned)f2b(x[3]) << 16),
              (unsigned)f2b(x[4]) | ((unsigned)f2b(x[5]) << 16),
              (unsigned)f2b(x[6]) | ((unsigned)f2b(x[7]) << 16)};
  *(uint4*)(hbf + base) = pk;
}

// ============ GEMM kernels: BK=64, conflict-free XOR swizzle ============
// LDS layout per operand tile: rows of 64 bf16 (128B) = 8 chunks of 16B.
// Swizzle (both sides): LDS[row][d] holds global[row][d ^ (row&7)].

// ---------- GEMM 128x128 tile, BK=64, 256 thr, 3-slot counted-vmcnt ----------
// EPI 0: out_bf16 = gelu(acc + bias)
// EPI 4: out_f32[z*M*N + idx] = acc   (split-K partial)
template <int EPI>
__global__ __launch_bounds__(256) void gemm_bt(
    const bf16* __restrict__ A, const bf16* __restrict__ Bt,
    const float* __restrict__ bias, float* __restrict__ outF,
    bf16* __restrict__ outB, int M, int N, int Klen, int lda, int ldb) {
  constexpr int ASZ = 128 * 64;          // 8192 elems
  constexpr int TILE = 2 * ASZ;          // A + B = 32 KB
  __shared__ bf16 lds[3 * TILE];         // 96 KB
  const int tid = threadIdx.x;
  const int wave = tid >> 6;
  const int lane = tid & 63;
  const int wm = (wave >> 1) * 64;
  const int wn = (wave & 1) * 64;

  const int bn = blockIdx.x;
  const int bm = blockIdx.y;
  const int rowA0 = bm * 128;
  const int rowB0 = bn * 128;
  const int k0 = blockIdx.z * Klen;

  const bf16* srcA[4];
  const bf16* srcB[4];
#pragma unroll
  for (int r = 0; r < 4; r++) {
    int c = r * 256 + tid;
    int row = c >> 3, d = c & 7;
    int cw = d ^ (row & 7);
    srcA[r] = A + (size_t)(rowA0 + row) * lda + k0 + cw * 8;
    srcB[r] = Bt + (size_t)(rowB0 + row) * ldb + k0 + cw * 8;
  }

  f32x4 acc[4][4];
#pragma unroll
  for (int i = 0; i < 4; i++)
#pragma unroll
    for (int j = 0; j < 4; j++) acc[i][j] = (f32x4){0.f, 0.f, 0.f, 0.f};

  const int fr = lane & 15;
  const int hi = lane >> 4;
  const int swz = fr & 7;

  auto STAGE = [&](int slot) {
    bf16* dst = lds + slot * TILE;
#pragma unroll
    for (int r = 0; r < 4; r++) {
      load16_lds(srcA[r], dst + (r * 4 + wave) * 512);
      srcA[r] += 64;
      load16_lds(srcB[r], dst + ASZ + (r * 4 + wave) * 512);
      srcB[r] += 64;
    }
  };

  STAGE(0);
  STAGE(1);
  const int nIter = Klen >> 6;
  int cur = 0, stg = 2;
  for (int it = 0; it < nIter; ++it) {
    if (it < nIter - 1)
      asm volatile("s_waitcnt vmcnt(8)" ::: "memory");
    else
      asm volatile("s_waitcnt vmcnt(0)" ::: "memory");
    __builtin_amdgcn_s_barrier();
    __builtin_amdgcn_sched_barrier(0);
    if (it + 2 < nIter) STAGE(stg);
    const bf16* lA = lds + cur * TILE;
    const bf16* lB = lA + ASZ;
#pragma unroll
    for (int ks = 0; ks < 2; ks++) {
      bf16x8 af[4], bfr[4];
#pragma unroll
      for (int f = 0; f < 4; f++) {
        int rowa = wm + f * 16 + fr;
        af[f] = *(const bf16x8*)(lA + rowa * 64 + ((ks * 4 + hi) ^ swz) * 8);
        int rowb = wn + f * 16 + fr;
        bfr[f] = *(const bf16x8*)(lB + rowb * 64 + ((ks * 4 + hi) ^ swz) * 8);
      }
#pragma unroll
      for (int i = 0; i < 4; i++)
#pragma unroll
        for (int j = 0; j < 4; j++)
          acc[i][j] = __builtin_amdgcn_mfma_f32_16x16x32_bf16(af[i], bfr[j], acc[i][j], 0, 0, 0);
    }
    cur = (cur == 2) ? 0 : cur + 1;
    stg = (stg == 2) ? 0 : stg + 1;
  }

  if constexpr (EPI == 4) outF += (size_t)blockIdx.z * M * N;
  const int orow = hi * 4;
  const int ocol = fr;
#pragma unroll
  for (int i = 0; i < 4; i++) {
#pragma unroll
    for (int j = 0; j < 4; j++) {
      int row0 = rowA0 + wm + i * 16 + orow;
      int col = rowB0 + wn + j * 16 + ocol;
#pragma unroll
      for (int q = 0; q < 4; q++) {
        float v = acc[i][j][q];
        size_t idx = (size_t)(row0 + q) * N + col;
        if constexpr (EPI == 0) {
          outB[idx] = (bf16)gelu_tanh(v + bias[col]);
        } else {
          outF[idx] = v;
        }
      }
    }
  }
}

// ---------- GEMM 256x128 tile, BK=64, 512 thr, 3-slot counted-vmcnt (gemm1) ----------
template <int EPI>
__global__ __launch_bounds__(512) void gemm_bt256(
    const bf16* __restrict__ A, const bf16* __restrict__ Bt,
    const float* __restrict__ bias, float* __restrict__ outF,
    bf16* __restrict__ outB, int M, int N, int lda, int ldb) {
  constexpr int ASZ = 256 * 64;          // 32 KB
  constexpr int BSZ = 128 * 64;          // 16 KB
  constexpr int TILE = ASZ + BSZ;        // 48 KB
  __shared__ bf16 lds[3 * TILE];         // 144 KB
  const int tid = threadIdx.x;
  const int wave = tid >> 6;
  const int lane = tid & 63;
  const int wm = (wave >> 1) * 64;
  const int wn = (wave & 1) * 64;

  const int bn = blockIdx.x;
  const int bm = blockIdx.y;
  const int rowA0 = bm * 256;
  const int rowB0 = bn * 128;

  const bf16* srcA[4];
#pragma unroll
  for (int r = 0; r < 4; r++) {
    int c = r * 512 + tid;
    int row = c >> 3, d = c & 7;
    int cw = d ^ (row & 7);
    srcA[r] = A + (size_t)(rowA0 + row) * lda + cw * 8;
  }
  const bf16* srcB[2];
#pragma unroll
  for (int r = 0; r < 2; r++) {
    int c = r * 512 + tid;
    int row = c >> 3, d = c & 7;
    int cw = d ^ (row & 7);
    srcB[r] = Bt + (size_t)(rowB0 + row) * ldb + cw * 8;
  }

  f32x4 acc[4][4];
#pragma unroll
  for (int i = 0; i < 4; i++)
#pragma unroll
    for (int j = 0; j < 4; j++) acc[i][j] = (f32x4){0.f, 0.f, 0.f, 0.f};

  const int fr = lane & 15;
  const int hi = lane >> 4;
  const int swz = fr & 7;

  auto STAGE = [&](int slot) {
    bf16* dst = lds + slot * TILE;
#pragma unroll
    for (int r = 0; r < 4; r++) {
      load16_lds(srcA[r], dst + (r * 8 + wave) * 512);
      srcA[r] += 64;
    }
#pragma unroll
    for (int r = 0; r < 2; r++) {
      load16_lds(srcB[r], dst + ASZ + (r * 8 + wave) * 512);
      srcB[r] += 64;
    }
  };

  STAGE(0);
  STAGE(1);
  const int nIter = 512 >> 6;  // 8 iters
  int cur = 0, stg = 2;
  for (int it = 0; it < nIter; ++it) {
    if (it < nIter - 1)
      asm volatile("s_waitcnt vmcnt(6)" ::: "memory");
    else
      asm volatile("s_waitcnt vmcnt(0)" ::: "memory");
    __builtin_amdgcn_s_barrier();
    __builtin_amdgcn_sched_barrier(0);
    if (it + 2 < nIter) STAGE(stg);
    const bf16* lA = lds + cur * TILE;
    const bf16* lB = lA + ASZ;
#pragma unroll
    for (int ks = 0; ks < 2; ks++) {
      bf16x8 af[4], bfr[4];
#pragma unroll
      for (int f = 0; f < 4; f++) {
        int rowa = wm + f * 16 + fr;
        af[f] = *(const bf16x8*)(lA + rowa * 64 + ((ks * 4 + hi) ^ swz) * 8);
        int rowb = wn + f * 16 + fr;
        bfr[f] = *(const bf16x8*)(lB + rowb * 64 + ((ks * 4 + hi) ^ swz) * 8);
      }
#pragma unroll
      for (int i = 0; i < 4; i++)
#pragma unroll
        for (int j = 0; j < 4; j++)
          acc[i][j] = __builtin_amdgcn_mfma_f32_16x16x32_bf16(af[i], bfr[j], acc[i][j], 0, 0, 0);
    }
    cur = (cur == 2) ? 0 : cur + 1;
    stg = (stg == 2) ? 0 : stg + 1;
  }

  const int orow = hi * 4;
  const int ocol = fr;
#pragma unroll
  for (int i = 0; i < 4; i++) {
#pragma unroll
    for (int j = 0; j < 4; j++) {
      int row0 = rowA0 + wm + i * 16 + orow;
      int col = rowB0 + wn + j * 16 + ocol;
#pragma unroll
      for (int q = 0; q < 4; q++) {
        float v = acc[i][j][q];
        size_t idx = (size_t)(row0 + q) * N + col;
        if constexpr (EPI == 0) {
          outB[idx] = (bf16)gelu_tanh(v + bias[col]);
        } else {
          outF[idx] = v;
        }
      }
    }
  }
}

// ---------- logits GEMM: 256x256 tile, BK=64, 512 thr, 2-slot 2-barrier ----------
__global__ __launch_bounds__(512, 1) void gemm_logits(
    const bf16* __restrict__ A, const bf16* __restrict__ Bt,
    float* __restrict__ outF, int M, int N, int lda, int ldb) {
  constexpr int ASZ = 256 * 64;     // 32 KB
  constexpr int TILE = 2 * ASZ;     // 64 KB
  __shared__ bf16 lds[2 * TILE];    // 128 KB
  const int tid = threadIdx.x;
  const int wave = tid >> 6;
  const int lane = tid & 63;
  const int wm = (wave >> 2) * 128;  // 0,128
  const int wn = (wave & 3) * 64;    // 0,64,128,192

  const int per = gridDim.x >> 3;
  const int wg = (blockIdx.x & 7) * per + (blockIdx.x >> 3);
  const int bm = wg & 15;
  const int bn = wg >> 4;
  const int rowA0 = bm * 256;
  const int rowB0 = bn * 256;

  const bf16* srcA[4];
  const bf16* srcB[4];
#pragma unroll
  for (int r = 0; r < 4; r++) {
    int c = r * 512 + tid;
    int row = c >> 3, d = c & 7;
    int cw = d ^ (row & 7);
    srcA[r] = A + (size_t)(rowA0 + row) * lda + cw * 8;
    srcB[r] = Bt + (size_t)(rowB0 + row) * ldb + cw * 8;
  }

  f32x4 acc[8][4];
#pragma unroll
  for (int i = 0; i < 8; i++)
#pragma unroll
    for (int j = 0; j < 4; j++) acc[i][j] = (f32x4){0.f, 0.f, 0.f, 0.f};

  const int fr = lane & 15;
  const int hi = lane >> 4;
  const int swz = fr & 7;

  auto STAGE = [&](int slot) {
    bf16* dst = lds + slot * TILE;
#pragma unroll
    for (int r = 0; r < 4; r++) {
      load16_lds(srcA[r], dst + (r * 8 + wave) * 512);
      srcA[r] += 64;
      load16_lds(srcB[r], dst + ASZ + (r * 8 + wave) * 512);
      srcB[r] += 64;
    }
  };

  STAGE(0);
  const int nIter = 512 >> 6;  // 8 iters
  for (int it = 0; it < nIter; ++it) {
    const int cur = it & 1;
    if (it + 1 < nIter) STAGE(cur ^ 1);
    if (it + 1 < nIter)
      asm volatile("s_waitcnt vmcnt(8)" ::: "memory");
    else
      asm volatile("s_waitcnt vmcnt(0)" ::: "memory");
    __builtin_amdgcn_s_barrier();
    __builtin_amdgcn_sched_barrier(0);
    const bf16* lA = lds + cur * TILE;
    const bf16* lB = lA + ASZ;
#pragma unroll
    for (int ks = 0; ks < 2; ks++) {
      bf16x8 af[8], bfr[4];
#pragma unroll
      for (int f = 0; f < 8; f++) {
        int rowa = wm + f * 16 + fr;
        af[f] = *(const bf16x8*)(lA + rowa * 64 + ((ks * 4 + hi) ^ swz) * 8);
      }
#pragma unroll
      for (int f = 0; f < 4; f++) {
        int rowb = wn + f * 16 + fr;
        bfr[f] = *(const bf16x8*)(lB + rowb * 64 + ((ks * 4 + hi) ^ swz) * 8);
      }
#pragma unroll
      for (int i = 0; i < 8; i++)
#pragma unroll
        for (int j = 0; j < 4; j++)
          acc[i][j] = __builtin_amdgcn_mfma_f32_16x16x32_bf16(af[i], bfr[j], acc[i][j], 0, 0, 0);
    }
    __builtin_amdgcn_s_barrier();
  }

  const int orow = hi * 4;
  const int ocol = fr;
#pragma unroll
  for (int i = 0; i < 8; i++) {
#pragma unroll
    for (int j = 0; j < 4; j++) {
      int row0 = rowA0 + wm + i * 16 + orow;
      int col = rowB0 + wn + j * 16 + ocol;
      if (col < N) {
#pragma unroll
        for (int q = 0; q < 4; q++)
          outF[(size_t)(row0 + q) * N + col] = acc[i][j][q];
      }
    }
  }
}

// ---------- launch ----------
extern "C" void kernel_launch(void* const* d_in, const int* in_sizes, int n_in,
                              void* d_out, int out_size, void* d_ws, size_t ws_size,
                              hipStream_t stream) {
  const int* ids = (const int*)d_in[0];
  const float* emb = (const float*)d_in[1];
  const float* hp_w = (const float*)d_in[2];
  const float* hp_b = (const float*)d_in[3];
  const float* ln_w = (const float*)d_in[4];
  const float* ln_b = (const float*)d_in[5];
  const float* W1 = (const float*)d_in[6];
  const float* b1 = (const float*)d_in[7];
  const float* W2 = (const float*)d_in[8];
  const float* b2 = (const float*)d_in[9];
  const float* lnf_w = (const float*)d_in[10];
  const float* lnf_b = (const float*)d_in[11];
  const float* eow = (const float*)d_in[12];
  float* out = (float*)d_out;

  char* ws = (char*)d_ws;
  float* h = (float*)(ws);                          // 8 MB
  bf16* ybf = (bf16*)(ws + (8u << 20));             // 4 MB
  bf16* abf = (bf16*)(ws + (12u << 20));            // 16 MB
  bf16* W1t = (bf16*)(ws + (28u << 20));            // 12 MB
  bf16* W2t = (bf16*)(ws + (40u << 20));            // 12 MB
  bf16* hpwB = (bf16*)(ws + (52u << 20));           // 0.5 MB
  bf16* eowB = (bf16*)(ws + (53u << 20));           // 51.6 MB (padded to Vpad rows)

  // split-K partials live in d_out's logits region (overwritten by logits GEMM later)
  float* p0 = out;                    // 2M floats
  float* p1 = out + (size_t)Md * Hd;  // next 2M floats

  // weight prep (2 launches total)
  {
    int n8hp = Hd * Hd / 8;
    int n8cast = Vd * Hd / 8, n8tot = Vpad * Hd / 8;
    int n8all = n8hp + n8tot;
    cast_weights<<<dim3((n8all + 255) / 256), dim3(256), 0, stream>>>(
        hp_w, hpwB, n8hp, eow, eowB, n8cast, n8tot);
  }
  transpose_cast2<<<dim3((Fd / 32) * (Hd / 32), 1, 2 * Ld), dim3(32, 8), 0, stream>>>(
      W1, W1t, W2, W2t);

  // one MLP layer: ln (with fused finish/gather) -> gemm1(256x128) -> split-K gemm2
  auto layer = [&](int l, int mode, const float* fb, const float* lw, const float* lb) {
    if (mode == 1)
      ln_rows<1><<<dim3(Md / 4), dim3(256), 0, stream>>>(h, p0, p1, fb, lw, lb, h, ybf,
                                                         nullptr, nullptr, nullptr);
    else if (mode == 2)
      ln_rows<2><<<dim3(Md / 4), dim3(256), 0, stream>>>(h, p0, p1, fb, lw, lb, h, ybf,
                                                         nullptr, nullptr, nullptr);
    else  // mode 3: gather+LN (first layer of stack 1)
      ln_rows<3><<<dim3(Md / 4), dim3(256), 0, stream>>>(h, p0, p1, fb, lw, lb, h, ybf,
                                                         ids, emb, nullptr);
    gemm_bt256<0><<<dim3(Fd / 128, Md / 256), dim3(512), 0, stream>>>(
        ybf, W1t + (size_t)l * Fd * Hd, b1 + (size_t)l * Fd, (float*)nullptr, abf,
        Md, Fd, Hd, Hd);
    gemm_bt<4><<<dim3(Hd / 128, Md / 128, 2), dim3(256), 0, stream>>>(
        abf, W2t + (size_t)l * Hd * Fd, (const float*)nullptr, p0, (bf16*)nullptr,
        Md, Hd, Fd / 2, Fd, Fd);
  };

  // ---- stack 1 ----
  layer(0, 3, nullptr, ln_w, ln_b);
  for (int l = 1; l < Ld; l++)
    layer(l, 1, b2 + (size_t)(l - 1) * Hd, ln_w + (size_t)l * Hd, ln_b + (size_t)l * Hd);
  finish2<<<dim3(Md * Hd / 8 / 256), dim3(256), 0, stream>>>(
      p0, p1, b2 + (size_t)(Ld - 1) * Hd, h, ybf);

  // ---- hp projection (split-K=2, finish fused into next LN) ----
  gemm_bt<4><<<dim3(Hd / 128, Md / 128, 2), dim3(256), 0, stream>>>(
      ybf, hpwB, (const float*)nullptr, p0, (bf16*)nullptr, Md, Hd, Hd / 2, Hd, Hd);

  // ---- stack 2 ----
  layer(0, 2, hp_b, ln_w, ln_b);
  for (int l = 1; l < Ld; l++)
    layer(l, 1, b2 + (size_t)(l - 1) * Hd, ln_w + (size_t)l * Hd, ln_b + (size_t)l * Hd);

  // ---- final LN (fused finish + tail write) + logits (256x256 BK=64, XCD swizzle) ----
  ln_rows<4><<<dim3(Md / 4), dim3(256), 0, stream>>>(
      h, p0, p1, b2 + (size_t)(Ld - 1) * Hd, lnf_w, lnf_b, h, ybf,
      nullptr, nullptr, out + (size_t)Md * Vd);
  gemm_logits<<<dim3((Vpad / 256) * (Md / 256)), dim3(512), 0, stream>>>(
      ybf, eowB, out, Md, Vd, Hd, Hd);
}